// Round 1
// baseline (2429.734 us; speedup 1.0000x reference)
//
#include <hip/hip_runtime.h>
#include <cstdint>
#include <cstddef>

// ---------------------------------------------------------------------------
// Show-Attend-Tell decoder on MI355X.
// Strategy: bf16 MFMA (16x16x32) for all matmuls, fp32 accumulate.
// One-time: convert features->bf16 (+mean), transpose all weights to [N][K]
// bf16, gather embeddings, att1 = features @ enc_w (big GEMM).
// Per step t: att2 GEMM -> fused e/relu/softmax kernel -> gate GEMM(sigmoid)
// -> awe weighted sum -> gates GEMM (split-K=4) -> LSTM pointwise -> y GEMM.
// ---------------------------------------------------------------------------

#define DEV __device__ __forceinline__

typedef __attribute__((ext_vector_type(8))) short s16x8;
typedef __attribute__((ext_vector_type(4))) float f32x4;

constexpr int Bb = 128, Pp = 196, Dd = 2048, Aa = 512, Ee = 512, Hh = 512, Vv = 10000;
constexpr int Tt = 19, TMAX = 20;
constexpr int KX = Ee + Dd + Hh;      // 3072 = concat(e_t, awe, h)
constexpr int NVP = 10048;            // V padded to 32-multiple

DEV float fbs(short s) {
    union { uint32_t u; float f; } v;
    v.u = ((uint32_t)(uint16_t)s) << 16;
    return v.f;
}
DEV short bfs(float f) {
    union { float f; uint32_t u; } v;
    v.f = f;
    uint32_t u = v.u;
    uint32_t r = (u + 0x7FFFu + ((u >> 16) & 1u)) >> 16;  // RNE
    return (short)(uint16_t)r;
}

// ---------------------------------------------------------------------------
// Generic bf16 MFMA GEMM:  C[M][N] = A[M][K] * B[N][K]^T   (B stored [N][K])
// LDS layout: [BK/8 k-chunks][rows][8 bf16] -> conflict-free ds_read_b128.
// EPI: 0 = bf16 out + bias (att1)
//      1 = f32 out (+bias +bias2 if non-null), zStride for split-K partials
//      2 = f32 sigmoid(out + bias)
//      3 = y output: (out + bias) * maskfactor, bounds n < V
// ---------------------------------------------------------------------------
template<int BM, int BN, int BK, int WR, int WC, int EPI>
__global__ __launch_bounds__(256) void gemm_k(
    const short* __restrict__ Ag, int lda,
    const short* __restrict__ Bg, int ldb,
    int Kc,
    float* __restrict__ outF, short* __restrict__ outH, int ldo, int zStride,
    const float* __restrict__ bias, const float* __restrict__ bias2,
    const int* __restrict__ lens, int t)
{
    constexpr int NCH = BK / 8;        // 16B k-chunks
    constexpr int AU = NCH * BM;       // 16B units in A tile
    constexpr int BU = NCH * BN;
    constexpr int APT = AU / 256;
    constexpr int BPT = BU / 256;
    constexpr int WM = BM / WR, WN = BN / WC;
    constexpr int FM = WM / 16, FN = WN / 16;

    __shared__ short sA[AU * 8];
    __shared__ short sB[BU * 8];

    const int tid = threadIdx.x, lane = tid & 63, wid = tid >> 6;
    const int l15 = lane & 15, l4 = lane >> 4;
    const int m0 = blockIdx.y * BM, n0 = blockIdx.x * BN;
    const int kStart = blockIdx.z * Kc;
    const int wr = wid / WC, wc = wid % WC;

    const f32x4 fz = {0.f, 0.f, 0.f, 0.f};
    f32x4 acc[FM][FN];
    #pragma unroll
    for (int i = 0; i < FM; ++i)
        #pragma unroll
        for (int j = 0; j < FN; ++j) acc[i][j] = fz;

    for (int kt = kStart; kt < kStart + Kc; kt += BK) {
        s16x8 ra[APT], rb[BPT];
        #pragma unroll
        for (int i = 0; i < APT; ++i) {
            int q = tid + 256 * i;
            int ch = q / BM, r = q % BM;
            ra[i] = *(const s16x8*)(Ag + (size_t)(m0 + r) * lda + kt + ch * 8);
        }
        #pragma unroll
        for (int i = 0; i < BPT; ++i) {
            int q = tid + 256 * i;
            int ch = q / BN, r = q % BN;
            rb[i] = *(const s16x8*)(Bg + (size_t)(n0 + r) * ldb + kt + ch * 8);
        }
        __syncthreads();
        #pragma unroll
        for (int i = 0; i < APT; ++i) { int q = tid + 256 * i; *(s16x8*)(sA + q * 8) = ra[i]; }
        #pragma unroll
        for (int i = 0; i < BPT; ++i) { int q = tid + 256 * i; *(s16x8*)(sB + q * 8) = rb[i]; }
        __syncthreads();
        #pragma unroll
        for (int ks = 0; ks < BK / 32; ++ks) {
            s16x8 af[FM], bf[FN];
            #pragma unroll
            for (int fm = 0; fm < FM; ++fm)
                af[fm] = *(const s16x8*)&sA[((ks * 4 + l4) * BM + wr * WM + fm * 16 + l15) * 8];
            #pragma unroll
            for (int fn = 0; fn < FN; ++fn)
                bf[fn] = *(const s16x8*)&sB[((ks * 4 + l4) * BN + wc * WN + fn * 16 + l15) * 8];
            #pragma unroll
            for (int fm = 0; fm < FM; ++fm)
                #pragma unroll
                for (int fn = 0; fn < FN; ++fn)
                    acc[fm][fn] = __builtin_amdgcn_mfma_f32_16x16x32_bf16(af[fm], bf[fn], acc[fm][fn], 0, 0, 0);
        }
    }

    #pragma unroll
    for (int fm = 0; fm < FM; ++fm)
        #pragma unroll
        for (int fn = 0; fn < FN; ++fn)
            #pragma unroll
            for (int r = 0; r < 4; ++r) {
                int m = m0 + wr * WM + fm * 16 + l4 * 4 + r;
                int n = n0 + wc * WN + fn * 16 + l15;
                float v = acc[fm][fn][r];
                if constexpr (EPI == 0) {
                    outH[(size_t)m * ldo + n] = bfs(v + bias[n]);
                } else if constexpr (EPI == 1) {
                    float bb = bias ? bias[n] : 0.f;
                    if (bias2) bb += bias2[n];
                    outF[(size_t)blockIdx.z * zStride + (size_t)m * ldo + n] = v + bb;
                } else if constexpr (EPI == 2) {
                    float x = v + bias[n];
                    outF[(size_t)m * ldo + n] = 1.f / (1.f + expf(-x));
                } else {
                    if (n < Vv) {
                        bool mf = t < lens[m] - 1;
                        outF[(size_t)m * ((size_t)Tt * Vv) + (size_t)t * Vv + n] = mf ? (v + bias[n]) : 0.f;
                    }
                }
            }
}

// ---------------------------------------------------------------------------
// features fp32 -> bf16 + mean over P.   grid (D/256, B)
// ---------------------------------------------------------------------------
__global__ __launch_bounds__(256) void conv_mean_k(
    const float* __restrict__ feat, short* __restrict__ featb, float* __restrict__ meanf)
{
    int b = blockIdx.y;
    int d = blockIdx.x * 256 + threadIdx.x;
    const float* f = feat + (size_t)b * Pp * Dd + d;
    short* o = featb + (size_t)b * Pp * Dd + d;
    float s = 0.f;
    for (int p = 0; p < Pp; ++p) {
        float v = f[(size_t)p * Dd];
        s += v;
        o[(size_t)p * Dd] = bfs(v);
    }
    meanf[(size_t)b * Dd + d] = s * (1.f / 196.f);
}

// h0/c0 init + write h into xin tail.  grid (2, B)
__global__ __launch_bounds__(256) void h0c0_k(
    const float* __restrict__ meanf,
    const float* __restrict__ hw, const float* __restrict__ hb,
    const float* __restrict__ cw, const float* __restrict__ cb,
    float* __restrict__ h_state, float* __restrict__ c_state, short* __restrict__ xin)
{
    int b = blockIdx.y;
    int j = blockIdx.x * 256 + threadIdx.x;
    __shared__ float sm[Dd];
    for (int i = threadIdx.x; i < Dd; i += 256) sm[i] = meanf[(size_t)b * Dd + i];
    __syncthreads();
    float sh = 0.f, sc = 0.f;
    for (int k = 0; k < Dd; ++k) {
        float m = sm[k];
        sh += m * hw[(size_t)k * Hh + j];
        sc += m * cw[(size_t)k * Hh + j];
    }
    sh += hb[j];
    sc += cb[j];
    h_state[(size_t)b * Hh + j] = sh;
    c_state[(size_t)b * Hh + j] = sc;
    xin[(size_t)b * KX + Ee + Dd + j] = bfs(sh);
}

// fp32 [R][C] -> bf16 [Cpad][dstStride] transpose (+zero pad).  grid(ceil(Cpad/32), ceil(R/32))
__global__ __launch_bounds__(256) void transpose_bf16(
    const float* __restrict__ src, int R, int C,
    short* __restrict__ dst, int dstStride, int colOff, int Cpad)
{
    __shared__ float tile[32][33];
    int c0 = blockIdx.x * 32, r0 = blockIdx.y * 32;
    int tx = threadIdx.x & 31, ty = threadIdx.x >> 5;
    #pragma unroll
    for (int i = 0; i < 4; ++i) {
        int r = r0 + ty + i * 8, c = c0 + tx;
        tile[ty + i * 8][tx] = (r < R && c < C) ? src[(size_t)r * C + c] : 0.f;
    }
    __syncthreads();
    #pragma unroll
    for (int i = 0; i < 4; ++i) {
        int cc = c0 + ty + i * 8, rr = r0 + tx;
        if (cc < Cpad && rr < R) dst[(size_t)cc * dstStride + colOff + rr] = bfs(tile[tx][ty + i * 8]);
    }
}

// embedding gather -> bf16 [T][B][E]
__global__ __launch_bounds__(256) void embg_k(
    const float* __restrict__ emb, const int* __restrict__ caps, short* __restrict__ embseq)
{
    size_t i = (size_t)blockIdx.x * 256 + threadIdx.x;
    if (i >= (size_t)Tt * Bb * Ee) return;
    int e = (int)(i % Ee);
    size_t r = i / Ee;
    int b = (int)(r % Bb);
    int t = (int)(r / Bb);
    int cap = caps[b * TMAX + t];
    embseq[i] = bfs(emb[(size_t)cap * Ee + e]);
}

// ---------------------------------------------------------------------------
// Fused: e_t copy into xin, e = relu(att1 + att2) @ att_w + att_b, softmax,
// alpha to ws, alpha*mf to output.  One block per batch row. 256 threads.
// ---------------------------------------------------------------------------
__global__ __launch_bounds__(256) void e_softmax_k(
    const short* __restrict__ att1, const float* __restrict__ att2b,
    const float* __restrict__ att_w, const float* __restrict__ att_b,
    const short* __restrict__ embt, short* __restrict__ xin,
    float* __restrict__ alphaw, float* __restrict__ alout,
    const int* __restrict__ lens, int t)
{
    int b = blockIdx.x, tid = threadIdx.x, lane = tid & 63, wid = tid >> 6;
    __shared__ float se[224];
    __shared__ float sred[256];

    // copy e_t (512 bf16 = 256 u32)
    ((uint32_t*)(xin + (size_t)b * KX))[tid] = ((const uint32_t*)(embt + (size_t)b * Ee))[tid];

    float aw[8], a2[8];
    #pragma unroll
    for (int j = 0; j < 8; ++j) {
        aw[j] = att_w[lane * 8 + j];
        a2[j] = att2b[(size_t)b * Aa + lane * 8 + j];
    }
    float ab = att_b[0];

    for (int p = wid; p < Pp; p += 4) {
        s16x8 row = *(const s16x8*)&att1[((size_t)b * Pp + p) * Aa + lane * 8];
        float s = 0.f;
        #pragma unroll
        for (int j = 0; j < 8; ++j) {
            float v = fbs(row[j]) + a2[j];
            v = v > 0.f ? v : 0.f;
            s += v * aw[j];
        }
        #pragma unroll
        for (int m = 32; m; m >>= 1) s += __shfl_xor(s, m);
        if (lane == 0) se[p] = s + ab;
    }
    __syncthreads();

    float e = (tid < Pp) ? se[tid] : -3.0e38f;
    sred[tid] = e;
    __syncthreads();
    for (int st = 128; st > 0; st >>= 1) {
        if (tid < st) sred[tid] = fmaxf(sred[tid], sred[tid + st]);
        __syncthreads();
    }
    float mx = sred[0];
    __syncthreads();
    float ex = (tid < Pp) ? expf(e - mx) : 0.f;
    sred[tid] = ex;
    __syncthreads();
    for (int st = 128; st > 0; st >>= 1) {
        if (tid < st) sred[tid] += sred[tid + st];
        __syncthreads();
    }
    float inv = 1.f / sred[0];
    if (tid < Pp) {
        float al = ex * inv;
        alphaw[(size_t)b * Pp + tid] = al;
        float mf = (t < lens[b] - 1) ? 1.f : 0.f;
        alout[(size_t)b * Tt * Pp + tid] = al * mf;
    }
}

// awe = gate * (alpha @ features) -> xin middle (bf16).  grid (4, B), 2 d per thread
__global__ __launch_bounds__(256) void awe_k(
    const short* __restrict__ featb, const float* __restrict__ alpha,
    const float* __restrict__ gate, short* __restrict__ xin)
{
    int b = blockIdx.y;
    int d0 = blockIdx.x * 512 + threadIdx.x * 2;
    __shared__ float sal[Pp];
    for (int i = threadIdx.x; i < Pp; i += 256) sal[i] = alpha[(size_t)b * Pp + i];
    __syncthreads();
    const short* f = featb + (size_t)b * Pp * Dd + d0;
    float s0 = 0.f, s1 = 0.f;
    for (int p = 0; p < Pp; ++p) {
        uint32_t v = *(const uint32_t*)(f + (size_t)p * Dd);
        float a = sal[p];
        s0 += a * fbs((short)(v & 0xFFFF));
        s1 += a * fbs((short)(v >> 16));
    }
    float g0 = gate[(size_t)b * Dd + d0], g1 = gate[(size_t)b * Dd + d0 + 1];
    uint32_t o = ((uint32_t)(uint16_t)bfs(g1 * s1) << 16) | (uint16_t)bfs(g0 * s0);
    *(uint32_t*)(xin + (size_t)b * KX + Ee + d0) = o;
}

// LSTM pointwise: sum 4 split-K partials + biases, cell update, masked state write
__global__ __launch_bounds__(256) void lstm_k(
    const float* __restrict__ gp, const float* __restrict__ b_ih, const float* __restrict__ b_hh,
    float* __restrict__ h_state, float* __restrict__ c_state,
    short* __restrict__ hnewb, short* __restrict__ xin,
    const int* __restrict__ lens, int t)
{
    int i = blockIdx.x * 256 + threadIdx.x;   // [0, B*H)
    int b = i >> 9, j = i & 511;
    size_t base = (size_t)b * 2048;
    auto G = [&](int col) {
        size_t o = base + col;
        float s = gp[o] + gp[o + 262144] + gp[o + 524288] + gp[o + 786432];
        return s + b_ih[col] + b_hh[col];
    };
    float ig = G(j), fg = G(512 + j), gg = G(1024 + j), og = G(1536 + j);
    float si = 1.f / (1.f + expf(-ig));
    float sf = 1.f / (1.f + expf(-fg));
    float so = 1.f / (1.f + expf(-og));
    float tg = tanhf(gg);
    float cn = sf * c_state[i] + si * tg;
    float hn = so * tanhf(cn);
    hnewb[i] = bfs(hn);
    bool m = t < lens[b] - 1;
    float hv = m ? hn : h_state[i];
    float cv = m ? cn : c_state[i];
    h_state[i] = hv;
    c_state[i] = cv;
    xin[(size_t)b * KX + Ee + Dd + j] = bfs(hv);
}

// ---------------------------------------------------------------------------
extern "C" void kernel_launch(void* const* d_in, const int* in_sizes, int n_in,
                              void* d_out, int out_size, void* d_ws, size_t ws_size,
                              hipStream_t stream)
{
    const float* features = (const float*)d_in[0];
    const int* captions   = (const int*)d_in[1];
    const int* lengths    = (const int*)d_in[2];
    const float* emb      = (const float*)d_in[3];
    const float* h_fc_w   = (const float*)d_in[4];
    const float* h_fc_b   = (const float*)d_in[5];
    const float* c_fc_w   = (const float*)d_in[6];
    const float* c_fc_b   = (const float*)d_in[7];
    const float* enc_w    = (const float*)d_in[8];
    const float* enc_b    = (const float*)d_in[9];
    const float* dec_w    = (const float*)d_in[10];
    const float* dec_b    = (const float*)d_in[11];
    const float* att_w    = (const float*)d_in[12];
    const float* att_b    = (const float*)d_in[13];
    const float* beta_w   = (const float*)d_in[14];
    const float* beta_b   = (const float*)d_in[15];
    const float* w_ih     = (const float*)d_in[16];
    const float* b_ih     = (const float*)d_in[17];
    const float* w_hh     = (const float*)d_in[18];
    const float* b_hh     = (const float*)d_in[19];
    const float* cls_w    = (const float*)d_in[20];
    const float* cls_b    = (const float*)d_in[21];

    char* w = (char*)d_ws;
    auto alloc = [&](size_t bytes) {
        char* p = w;
        w += (bytes + 255) & ~(size_t)255;
        return p;
    };
    short* featb  = (short*)alloc((size_t)Bb * Pp * Dd * 2);
    short* att1   = (short*)alloc((size_t)Bb * Pp * Aa * 2);
    short* encT   = (short*)alloc((size_t)Aa * Dd * 2);
    short* combT  = (short*)alloc((size_t)2048 * KX * 2);
    short* clsT   = (short*)alloc((size_t)NVP * Hh * 2);
    short* betaT  = (short*)alloc((size_t)Dd * Hh * 2);
    short* decT   = (short*)alloc((size_t)Aa * Hh * 2);
    short* embseq = (short*)alloc((size_t)Tt * Bb * Ee * 2);
    float* meanf  = (float*)alloc((size_t)Bb * Dd * 4);
    float* h_state = (float*)alloc((size_t)Bb * Hh * 4);
    float* c_state = (float*)alloc((size_t)Bb * Hh * 4);
    float* att2b  = (float*)alloc((size_t)Bb * Aa * 4);
    float* alphaw = (float*)alloc((size_t)Bb * Pp * 4);
    float* gatebuf = (float*)alloc((size_t)Bb * Dd * 4);
    float* gatesp = (float*)alloc((size_t)4 * Bb * 2048 * 4);
    short* xin    = (short*)alloc((size_t)Bb * KX * 2);
    short* hnewb  = (short*)alloc((size_t)Bb * Hh * 2);

    float* y_out  = (float*)d_out;
    float* al_out = y_out + (size_t)Bb * Tt * Vv;

    // ---- precompute ----
    conv_mean_k<<<dim3(8, 128), 256, 0, stream>>>(features, featb, meanf);
    h0c0_k<<<dim3(2, 128), 256, 0, stream>>>(meanf, h_fc_w, h_fc_b, c_fc_w, c_fc_b, h_state, c_state, xin);
    transpose_bf16<<<dim3(16, 64), 256, 0, stream>>>(enc_w, 2048, 512, encT, 2048, 0, 512);
    transpose_bf16<<<dim3(64, 80), 256, 0, stream>>>(w_ih, 2560, 2048, combT, KX, 0, 2048);
    transpose_bf16<<<dim3(64, 16), 256, 0, stream>>>(w_hh, 512, 2048, combT, KX, 2560, 2048);
    transpose_bf16<<<dim3(314, 16), 256, 0, stream>>>(cls_w, 512, 10000, clsT, 512, 0, NVP);
    transpose_bf16<<<dim3(64, 16), 256, 0, stream>>>(beta_w, 512, 2048, betaT, 512, 0, 2048);
    transpose_bf16<<<dim3(16, 16), 256, 0, stream>>>(dec_w, 512, 512, decT, 512, 0, 512);
    embg_k<<<(Tt * Bb * Ee + 255) / 256, 256, 0, stream>>>(emb, captions, embseq);
    // att1 = features @ enc_w + enc_b  (bf16 out)
    gemm_k<128, 64, 64, 2, 2, 0><<<dim3(8, 196), 256, 0, stream>>>(
        featb, Dd, encT, Dd, Dd, nullptr, att1, Aa, 0, enc_b, nullptr, nullptr, 0);

    // ---- decode steps ----
    for (int t = 0; t < Tt; ++t) {
        // att2 = h @ dec_w + dec_b
        gemm_k<128, 32, 64, 4, 1, 1><<<dim3(16, 1), 256, 0, stream>>>(
            xin + Ee + Dd, KX, decT, Hh, Hh, att2b, nullptr, Aa, 0, dec_b, nullptr, nullptr, 0);
        // e, softmax, alpha (+e_t copy)
        e_softmax_k<<<128, 256, 0, stream>>>(
            att1, att2b, att_w, att_b, embseq + (size_t)t * Bb * Ee, xin,
            alphaw, al_out + (size_t)t * Pp, lengths, t);
        // gate = sigmoid(h @ beta_w + beta_b)
        gemm_k<128, 32, 64, 4, 1, 2><<<dim3(64, 1), 256, 0, stream>>>(
            xin + Ee + Dd, KX, betaT, Hh, Hh, gatebuf, nullptr, Dd, 0, beta_b, nullptr, nullptr, 0);
        // awe = gate * (alpha @ features) -> xin
        awe_k<<<dim3(4, 128), 256, 0, stream>>>(featb, alphaw, gatebuf, xin);
        // gates = xin @ [w_ih;w_hh]  (split-K = 4, partials)
        gemm_k<128, 32, 64, 4, 1, 1><<<dim3(64, 1, 4), 256, 0, stream>>>(
            xin, KX, combT, KX, KX / 4, gatesp, nullptr, 2048, Bb * 2048, nullptr, nullptr, nullptr, 0);
        // LSTM pointwise
        lstm_k<<<(Bb * Hh) / 256, 256, 0, stream>>>(
            gatesp, b_ih, b_hh, h_state, c_state, hnewb, xin, lengths, t);
        // y = (h_new @ cls_w + cls_b) * mf
        gemm_k<128, 32, 64, 4, 1, 3><<<dim3(NVP / 32, 1), 256, 0, stream>>>(
            hnewb, Hh, clsT, Hh, Hh, y_out, nullptr, Vv, 0, cls_b, nullptr, lengths, t);
    }
}

// Round 2
// 1882.642 us; speedup vs baseline: 1.2906x; 1.2906x over previous
//
#include <hip/hip_runtime.h>
#include <cstdint>
#include <cstddef>

// ---------------------------------------------------------------------------
// Show-Attend-Tell decoder on MI355X (round 2).
// bf16 MFMA 16x16x32 everywhere, fp32 accumulate.
// - att1 GEMM: BM=128/BN=256/512thr, A re-fetch 2x (was 8x).
// - h0/c0 via MFMA GEMM (was 1GB naive re-read).
// - per step: [att2+gate fused GEMM] -> [e/softmax] -> [awe] ->
//             [gates GEMM + fused LSTM epilogue, quad-permuted weights].
// - xin double-buffered by step parity (avoids cross-block h-slot race).
// - y deferred: ONE GEMM (19*128 x 10048) after the loop, XCD-chunked remap.
// - All GEMM staging: coalesced row-major global loads + XOR-swizzled LDS
//   (same swizzle expr on write & read -> conflict-free, math-identical).
// ---------------------------------------------------------------------------

#define DEV __device__ __forceinline__

typedef __attribute__((ext_vector_type(8))) short s16x8;
typedef __attribute__((ext_vector_type(4))) float f32x4;

constexpr int Bb = 128, Pp = 196, Dd = 2048, Aa = 512, Ee = 512, Hh = 512, Vv = 10000;
constexpr int Tt = 19, TMAX = 20;
constexpr int KX = Ee + Dd + Hh;      // 3072
constexpr int NVP = 10048;            // V padded to 64

DEV float fbs(short s) {
    union { uint32_t u; float f; } v;
    v.u = ((uint32_t)(uint16_t)s) << 16;
    return v.f;
}
DEV short bfs(float f) {
    union { float f; uint32_t u; } v;
    v.f = f;
    uint32_t u = v.u;
    uint32_t r = (u + 0x7FFFu + ((u >> 16) & 1u)) >> 16;  // RNE
    return (short)(uint16_t)r;
}

// ---------------------------------------------------------------------------
// Generic bf16 MFMA GEMM: C[M][N] = A[M][K] * B[N][K]^T  (B stored [N][K])
// LDS: row-major [row][NCH chunks of 16B], chunk slot XOR-swizzled by row&7.
// EPI: 0 = bf16 out + bias (att1)
//      3 = deferred y: 1-D grid, XCD-chunked remap over (npanel,trow) tasks
//      4 = cat: n<512 -> att2b f32 (+dec_b); else gatebuf sigmoid (+beta_b)
//      5 = gates + fused LSTM epilogue (quad-permuted N layout)
//      6 = h0c0: n<512 -> xin h-slot bf16 (+h_fc_b); else c_state (+c_fc_b)
// ---------------------------------------------------------------------------
template<int BM, int BN, int BK, int TH, int WR, int WC, int EPI>
__global__ __launch_bounds__(TH) void gemm_k(
    const short* __restrict__ Ag, int lda,
    const short* __restrict__ Bg, int ldb,
    int K,
    float* __restrict__ outF, float* __restrict__ outF2,
    short* __restrict__ outH, short* __restrict__ outH2,
    int ldo,
    const float* __restrict__ bias, const float* __restrict__ bias2,
    const int* __restrict__ lens, int t)
{
    constexpr int NCH = BK / 8;
    constexpr int AU = NCH * BM, BU = NCH * BN;
    constexpr int APT = AU / TH, BPT = BU / TH;
    constexpr int WM = BM / WR, WN = BN / WC;
    constexpr int FM = WM / 16, FN = WN / 16;
    static_assert(AU % TH == 0 && BU % TH == 0, "staging divisibility");
    static_assert(WR * WC == TH / 64, "wave layout");

    __shared__ __align__(16) short sA[AU * 8];
    __shared__ __align__(16) short sB[BU * 8];

    const int tid = threadIdx.x, lane = tid & 63, wid = tid >> 6;
    const int l15 = lane & 15, l4 = lane >> 4;

    int m0, n0, trow_ = 0;
    if constexpr (EPI == 3) {
        const int nwg = (int)gridDim.x;           // 157 * 19
        const int qq = nwg >> 3, rr = nwg & 7;
        int xcd = (int)blockIdx.x & 7, idx = (int)blockIdx.x >> 3;
        int task = (xcd < rr) ? xcd * (qq + 1) + idx
                              : rr * (qq + 1) + (xcd - rr) * qq + idx;
        int npanel = task / Tt;
        trow_ = task - npanel * Tt;
        m0 = trow_ * BM;
        n0 = npanel * BN;
    } else {
        m0 = blockIdx.y * BM;
        n0 = blockIdx.x * BN;
    }
    const int wr = wid / WC, wc = wid % WC;

    const f32x4 fz = {0.f, 0.f, 0.f, 0.f};
    f32x4 acc[FM][FN];
    #pragma unroll
    for (int i = 0; i < FM; ++i)
        #pragma unroll
        for (int j = 0; j < FN; ++j) acc[i][j] = fz;

    for (int kt = 0; kt < K; kt += BK) {
        s16x8 ra[APT], rb[BPT];
        #pragma unroll
        for (int i = 0; i < APT; ++i) {
            int q2 = tid + TH * i;
            int r2 = q2 / NCH, ch = q2 % NCH;
            ra[i] = *(const s16x8*)(Ag + (size_t)(m0 + r2) * lda + kt + ch * 8);
        }
        #pragma unroll
        for (int i = 0; i < BPT; ++i) {
            int q2 = tid + TH * i;
            int r2 = q2 / NCH, ch = q2 % NCH;
            rb[i] = *(const s16x8*)(Bg + (size_t)(n0 + r2) * ldb + kt + ch * 8);
        }
        __syncthreads();
        #pragma unroll
        for (int i = 0; i < APT; ++i) {
            int q2 = tid + TH * i;
            int r2 = q2 / NCH, ch = q2 % NCH;
            *(s16x8*)(sA + (r2 * NCH + (ch ^ (r2 & 7))) * 8) = ra[i];
        }
        #pragma unroll
        for (int i = 0; i < BPT; ++i) {
            int q2 = tid + TH * i;
            int r2 = q2 / NCH, ch = q2 % NCH;
            *(s16x8*)(sB + (r2 * NCH + (ch ^ (r2 & 7))) * 8) = rb[i];
        }
        __syncthreads();
        #pragma unroll
        for (int ks = 0; ks < BK / 32; ++ks) {
            s16x8 af[FM], bf[FN];
            #pragma unroll
            for (int fm = 0; fm < FM; ++fm) {
                int rr2 = wr * WM + fm * 16 + l15, cc = ks * 4 + l4;
                af[fm] = *(const s16x8*)&sA[(rr2 * NCH + (cc ^ (rr2 & 7))) * 8];
            }
            #pragma unroll
            for (int fn = 0; fn < FN; ++fn) {
                int rr2 = wc * WN + fn * 16 + l15, cc = ks * 4 + l4;
                bf[fn] = *(const s16x8*)&sB[(rr2 * NCH + (cc ^ (rr2 & 7))) * 8];
            }
            #pragma unroll
            for (int fm = 0; fm < FM; ++fm)
                #pragma unroll
                for (int fn = 0; fn < FN; ++fn)
                    acc[fm][fn] = __builtin_amdgcn_mfma_f32_16x16x32_bf16(af[fm], bf[fn], acc[fm][fn], 0, 0, 0);
        }
    }

    if constexpr (EPI == 5) {
        // ---- fused LSTM epilogue (quad-permuted cols: n' = q*4+g, src col g*512+q)
        float* sE = (float*)sA;                 // BM*BN*4 bytes <= sizeof(sA)
        static_assert(BM * BN * 4 <= AU * 16, "sE fits in sA");
        __syncthreads();
        #pragma unroll
        for (int fm = 0; fm < FM; ++fm)
            #pragma unroll
            for (int fn = 0; fn < FN; ++fn)
                #pragma unroll
                for (int r2 = 0; r2 < 4; ++r2) {
                    int ml = wr * WM + fm * 16 + l4 * 4 + r2;
                    int nl = wc * WN + fn * 16 + l15;
                    sE[ml * BN + nl] = acc[fm][fn][r2];
                }
        __syncthreads();
        const int q0 = n0 >> 2;
        constexpr int ITEMS = (BM * (BN / 4)) / TH;
        #pragma unroll
        for (int i = 0; i < ITEMS; ++i) {
            int item = i * TH + tid;
            int bl = item >> 3, jl = item & 7;   // BN/4 == 8
            int b = m0 + bl;
            int q = q0 + jl;
            f32x4 ge = *(const f32x4*)&sE[bl * BN + jl * 4];
            float gi = ge[0] + bias[q]        + bias2[q];
            float gf = ge[1] + bias[512 + q]  + bias2[512 + q];
            float gg = ge[2] + bias[1024 + q] + bias2[1024 + q];
            float go = ge[3] + bias[1536 + q] + bias2[1536 + q];
            float si = 1.f / (1.f + expf(-gi));
            float sf = 1.f / (1.f + expf(-gf));
            float so = 1.f / (1.f + expf(-go));
            float tg = tanhf(gg);
            int sidx = b * 512 + q;
            float cn = sf * outF2[sidx] + si * tg;
            float hn = so * tanhf(cn);
            outH[(size_t)t * (128 * 512) + sidx] = bfs(hn);     // hnew_all[t]
            if (t < lens[b] - 1) {
                outF2[sidx] = cn;                                // c_state
                outH2[(size_t)b * KX + 2560 + q] = bfs(hn);      // xin(next) h-slot
            }
        }
    } else {
        #pragma unroll
        for (int fm = 0; fm < FM; ++fm)
            #pragma unroll
            for (int fn = 0; fn < FN; ++fn)
                #pragma unroll
                for (int r2 = 0; r2 < 4; ++r2) {
                    int ml = wr * WM + fm * 16 + l4 * 4 + r2;
                    int nl = wc * WN + fn * 16 + l15;
                    int m = m0 + ml, n = n0 + nl;
                    float v = acc[fm][fn][r2];
                    if constexpr (EPI == 0) {
                        outH[(size_t)m * ldo + n] = bfs(v + bias[n]);
                    } else if constexpr (EPI == 3) {
                        if (n < Vv) {
                            bool mk = trow_ < lens[ml] - 1;     // ml == b (BM=128)
                            outF[((size_t)ml * Tt + trow_) * Vv + n] = mk ? (v + bias[n]) : 0.f;
                        }
                    } else if constexpr (EPI == 4) {
                        if (n < 512) outF[(size_t)m * Aa + n] = v + bias[n];
                        else outF2[(size_t)m * Dd + (n - 512)] =
                                 1.f / (1.f + expf(-(v + bias2[n - 512])));
                    } else if constexpr (EPI == 6) {
                        if (n < 512) {
                            float hv = v + bias[n];
                            outH2[(size_t)m * KX + 2560 + n] = bfs(hv);   // xin0 h-slot
                        } else {
                            outF2[(size_t)m * 512 + (n - 512)] = v + bias2[n - 512]; // c_state
                        }
                    }
                }
    }
}

// ---------------------------------------------------------------------------
// features fp32 -> bf16, plus bf16 mean over P.  grid (2, B), 4 d/thread.
// ---------------------------------------------------------------------------
__global__ __launch_bounds__(256) void conv_mean_k(
    const float* __restrict__ feat, short* __restrict__ featb, short* __restrict__ meanb)
{
    int b = blockIdx.y;
    int d = (blockIdx.x * 256 + threadIdx.x) * 4;
    const float* f = feat + (size_t)b * Pp * Dd + d;
    short* o = featb + (size_t)b * Pp * Dd + d;
    float s0 = 0.f, s1 = 0.f, s2 = 0.f, s3 = 0.f;
    for (int p = 0; p < Pp; ++p) {
        float4 v = *(const float4*)(f + (size_t)p * Dd);
        s0 += v.x; s1 += v.y; s2 += v.z; s3 += v.w;
        short4 ov = make_short4(bfs(v.x), bfs(v.y), bfs(v.z), bfs(v.w));
        *(short4*)(o + (size_t)p * Dd) = ov;
    }
    const float inv = 1.f / 196.f;
    short4 mv = make_short4(bfs(s0 * inv), bfs(s1 * inv), bfs(s2 * inv), bfs(s3 * inv));
    *(short4*)(meanb + (size_t)b * Dd + d) = mv;
}

// fp32 [R][C] -> bf16 [perm(c)][dstStride] transpose (+zero pad rows >= C).
// PERM=1: dst row = (c%512)*4 + c/512  (quad-permuted gate layout, C==2048).
template<int PERM>
__global__ __launch_bounds__(256) void transpose_bf16(
    const float* __restrict__ src, int R, int C,
    short* __restrict__ dst, int dstStride, int colOff, int Cpad)
{
    __shared__ float tile[32][33];
    int c0 = blockIdx.x * 32, r0 = blockIdx.y * 32;
    int tx = threadIdx.x & 31, ty = threadIdx.x >> 5;
    #pragma unroll
    for (int i = 0; i < 4; ++i) {
        int r = r0 + ty + i * 8, c = c0 + tx;
        tile[ty + i * 8][tx] = (r < R && c < C) ? src[(size_t)r * C + c] : 0.f;
    }
    __syncthreads();
    #pragma unroll
    for (int i = 0; i < 4; ++i) {
        int cc = c0 + ty + i * 8, rr = r0 + tx;
        if (cc < Cpad && rr < R) {
            int drow = PERM ? ((cc & 511) * 4 + (cc >> 9)) : cc;
            dst[(size_t)drow * dstStride + colOff + rr] = bfs(tile[tx][ty + i * 8]);
        }
    }
}

// embedding gather -> bf16 [T][B][E]
__global__ __launch_bounds__(256) void embg_k(
    const float* __restrict__ emb, const int* __restrict__ caps, short* __restrict__ embseq)
{
    size_t i = (size_t)blockIdx.x * 256 + threadIdx.x;
    if (i >= (size_t)Tt * Bb * Ee) return;
    int e = (int)(i % Ee);
    size_t r = i / Ee;
    int b = (int)(r % Bb);
    int t = (int)(r / Bb);
    int cap = caps[b * TMAX + t];
    embseq[i] = bfs(emb[(size_t)cap * Ee + e]);
}

// ---------------------------------------------------------------------------
// Fused: e_t copy into xin, e = relu(att1+att2)@att_w + att_b, softmax,
// alpha -> ws, alpha*mf -> output.  One block per b, 512 threads (8 waves).
// ---------------------------------------------------------------------------
__global__ __launch_bounds__(512) void e_softmax_k(
    const short* __restrict__ att1, const float* __restrict__ att2b,
    const float* __restrict__ att_w, const float* __restrict__ att_b,
    const short* __restrict__ embt, short* __restrict__ xin,
    float* __restrict__ alphaw, float* __restrict__ alout,
    const int* __restrict__ lens, int t)
{
    int b = blockIdx.x, tid = threadIdx.x, lane = tid & 63, wid = tid >> 6;
    __shared__ float se[224];
    __shared__ float sred[256];

    if (tid < 256)
        ((uint32_t*)(xin + (size_t)b * KX))[tid] = ((const uint32_t*)(embt + (size_t)b * Ee))[tid];

    float aw[8], a2[8];
    #pragma unroll
    for (int j = 0; j < 8; ++j) {
        aw[j] = att_w[lane * 8 + j];
        a2[j] = att2b[(size_t)b * Aa + lane * 8 + j];
    }
    float ab = att_b[0];

    for (int p = wid; p < Pp; p += 8) {
        s16x8 row = *(const s16x8*)&att1[((size_t)b * Pp + p) * Aa + lane * 8];
        float s = 0.f;
        #pragma unroll
        for (int j = 0; j < 8; ++j) {
            float v = fbs(row[j]) + a2[j];
            v = v > 0.f ? v : 0.f;
            s += v * aw[j];
        }
        #pragma unroll
        for (int m = 32; m; m >>= 1) s += __shfl_xor(s, m);
        if (lane == 0) se[p] = s + ab;
    }
    __syncthreads();

    float e = 0.f, ex = 0.f;
    if (tid < 256) {
        e = (tid < Pp) ? se[tid] : -3.0e38f;
        sred[tid] = e;
    }
    __syncthreads();
    for (int st = 128; st > 0; st >>= 1) {
        if (tid < st) sred[tid] = fmaxf(sred[tid], sred[tid + st]);
        __syncthreads();
    }
    float mx = sred[0];
    __syncthreads();
    if (tid < 256) {
        ex = (tid < Pp) ? expf(e - mx) : 0.f;
        sred[tid] = ex;
    }
    __syncthreads();
    for (int st = 128; st > 0; st >>= 1) {
        if (tid < st) sred[tid] += sred[tid + st];
        __syncthreads();
    }
    float inv = 1.f / sred[0];
    if (tid < Pp) {
        float al = ex * inv;
        alphaw[(size_t)b * Pp + tid] = al;
        float mf = (t < lens[b] - 1) ? 1.f : 0.f;
        alout[(size_t)b * Tt * Pp + tid] = al * mf;
    }
}

// awe = gate * (alpha @ features) -> xin mid (bf16).  grid (2, B), 4 d/thread.
__global__ __launch_bounds__(256) void awe_k(
    const short* __restrict__ featb, const float* __restrict__ alpha,
    const float* __restrict__ gate, short* __restrict__ xin)
{
    int b = blockIdx.y;
    int d0 = (blockIdx.x * 256 + threadIdx.x) * 4;
    __shared__ float sal[Pp];
    for (int i = threadIdx.x; i < Pp; i += 256) sal[i] = alpha[(size_t)b * Pp + i];
    __syncthreads();
    const short* f = featb + (size_t)b * Pp * Dd + d0;
    float s0 = 0.f, s1 = 0.f, s2 = 0.f, s3 = 0.f;
    #pragma unroll 2
    for (int p = 0; p < Pp; ++p) {
        uint2 v = *(const uint2*)(f + (size_t)p * Dd);
        float a = sal[p];
        s0 += a * fbs((short)(v.x & 0xFFFF));
        s1 += a * fbs((short)(v.x >> 16));
        s2 += a * fbs((short)(v.y & 0xFFFF));
        s3 += a * fbs((short)(v.y >> 16));
    }
    const float* g = gate + (size_t)b * Dd + d0;
    short4 o = make_short4(bfs(g[0] * s0), bfs(g[1] * s1), bfs(g[2] * s2), bfs(g[3] * s3));
    *(short4*)(xin + (size_t)b * KX + Ee + d0) = o;
}

// ---------------------------------------------------------------------------
extern "C" void kernel_launch(void* const* d_in, const int* in_sizes, int n_in,
                              void* d_out, int out_size, void* d_ws, size_t ws_size,
                              hipStream_t stream)
{
    const float* features = (const float*)d_in[0];
    const int* captions   = (const int*)d_in[1];
    const int* lengths    = (const int*)d_in[2];
    const float* emb      = (const float*)d_in[3];
    const float* h_fc_w   = (const float*)d_in[4];
    const float* h_fc_b   = (const float*)d_in[5];
    const float* c_fc_w   = (const float*)d_in[6];
    const float* c_fc_b   = (const float*)d_in[7];
    const float* enc_w    = (const float*)d_in[8];
    const float* enc_b    = (const float*)d_in[9];
    const float* dec_w    = (const float*)d_in[10];
    const float* dec_b    = (const float*)d_in[11];
    const float* att_w    = (const float*)d_in[12];
    const float* att_b    = (const float*)d_in[13];
    const float* beta_w   = (const float*)d_in[14];
    const float* beta_b   = (const float*)d_in[15];
    const float* w_ih     = (const float*)d_in[16];
    const float* b_ih     = (const float*)d_in[17];
    const float* w_hh     = (const float*)d_in[18];
    const float* b_hh     = (const float*)d_in[19];
    const float* cls_w    = (const float*)d_in[20];
    const float* cls_b    = (const float*)d_in[21];

    char* w = (char*)d_ws;
    auto alloc = [&](size_t bytes) {
        char* p = w;
        w += (bytes + 255) & ~(size_t)255;
        return p;
    };
    short* featb    = (short*)alloc((size_t)Bb * Pp * Dd * 2);
    short* att1b    = (short*)alloc((size_t)Bb * Pp * Aa * 2);
    short* encT     = (short*)alloc((size_t)Aa * Dd * 2);
    short* combT    = (short*)alloc((size_t)2048 * KX * 2);   // quad-permuted
    short* clsT     = (short*)alloc((size_t)NVP * Hh * 2);
    short* catT     = (short*)alloc((size_t)2560 * Hh * 2);   // [dec;beta]
    short* hcT      = (short*)alloc((size_t)1024 * Dd * 2);   // [h_fc;c_fc]
    short* embseq   = (short*)alloc((size_t)Tt * Bb * Ee * 2);
    short* meanb    = (short*)alloc((size_t)Bb * Dd * 2);
    float* c_state  = (float*)alloc((size_t)Bb * Hh * 4);
    float* att2b    = (float*)alloc((size_t)Bb * Aa * 4);
    float* alphaw   = (float*)alloc((size_t)Bb * Pp * 4);
    float* gatebuf  = (float*)alloc((size_t)Bb * Dd * 4);
    short* xin0     = (short*)alloc((size_t)Bb * KX * 2);
    short* xin1     = (short*)alloc((size_t)Bb * KX * 2);
    short* hnew_all = (short*)alloc((size_t)Tt * Bb * Hh * 2);

    float* y_out  = (float*)d_out;
    float* al_out = y_out + (size_t)Bb * Tt * Vv;

    // ---- precompute ----
    conv_mean_k<<<dim3(2, 128), 256, 0, stream>>>(features, featb, meanb);
    transpose_bf16<0><<<dim3(16, 64), 256, 0, stream>>>(enc_w, 2048, 512, encT, 2048, 0, 512);
    transpose_bf16<0><<<dim3(16, 64), 256, 0, stream>>>(h_fc_w, 2048, 512, hcT, 2048, 0, 512);
    transpose_bf16<0><<<dim3(16, 64), 256, 0, stream>>>(c_fc_w, 2048, 512, hcT + (size_t)512 * 2048, 2048, 0, 512);
    transpose_bf16<0><<<dim3(16, 16), 256, 0, stream>>>(dec_w, 512, 512, catT, 512, 0, 512);
    transpose_bf16<0><<<dim3(64, 16), 256, 0, stream>>>(beta_w, 512, 2048, catT + (size_t)512 * 512, 512, 0, 2048);
    transpose_bf16<1><<<dim3(64, 80), 256, 0, stream>>>(w_ih, 2560, 2048, combT, KX, 0, 2048);
    transpose_bf16<1><<<dim3(64, 16), 256, 0, stream>>>(w_hh, 512, 2048, combT, KX, 2560, 2048);
    transpose_bf16<0><<<dim3(314, 16), 256, 0, stream>>>(cls_w, 512, 10000, clsT, 512, 0, NVP);
    embg_k<<<(Tt * Bb * Ee + 255) / 256, 256, 0, stream>>>(emb, captions, embseq);

    // h0/c0: meanb[128][2048] @ hcT[1024][2048]^T  (EPI 6)
    gemm_k<128, 64, 64, 256, 2, 2, 6><<<dim3(16, 1), 256, 0, stream>>>(
        meanb, 2048, hcT, 2048, 2048,
        nullptr, c_state, nullptr, xin0, 0, h_fc_b, c_fc_b, nullptr, 0);

    // att1 = features @ enc_w + enc_b (bf16 out), BN=256, 512 threads
    gemm_k<128, 256, 64, 512, 2, 4, 0><<<dim3(2, 196), 512, 0, stream>>>(
        featb, 2048, encT, 2048, 2048,
        nullptr, nullptr, att1b, nullptr, Aa, enc_b, nullptr, nullptr, 0);

    // ---- decode steps ----
    for (int t = 0; t < Tt; ++t) {
        short* xc = (t & 1) ? xin1 : xin0;
        short* xn = (t & 1) ? xin0 : xin1;
        // att2 (f32) + gate (sigmoid f32) fused: h @ [dec;beta]
        gemm_k<128, 64, 64, 256, 2, 2, 4><<<dim3(40, 1), 256, 0, stream>>>(
            xc + 2560, KX, catT, 512, 512,
            att2b, gatebuf, nullptr, nullptr, 0, dec_b, beta_b, nullptr, 0);
        // e, softmax, alpha (+e_t copy into xc)
        e_softmax_k<<<128, 512, 0, stream>>>(
            att1b, att2b, att_w, att_b, embseq + (size_t)t * Bb * Ee, xc,
            alphaw, al_out + (size_t)t * Pp, lengths, t);
        // awe = gate * (alpha @ features) -> xc
        awe_k<<<dim3(2, 128), 256, 0, stream>>>(featb, alphaw, gatebuf, xc);
        // gates = xc @ comb (quad-permuted) + fused LSTM -> c_state, hnew_all, xn
        gemm_k<64, 32, 128, 256, 4, 1, 5><<<dim3(64, 2), 256, 0, stream>>>(
            xc, KX, combT, KX, KX,
            nullptr, c_state, hnew_all, xn, 0, b_ih, b_hh, lengths, t);
    }

    // deferred y: hnew_all[2432][512] @ clsT[10048][512]^T, XCD-chunked 1-D grid
    gemm_k<128, 64, 64, 256, 2, 2, 3><<<dim3(157 * Tt), 256, 0, stream>>>(
        hnew_all, 512, clsT, 512, 512,
        y_out, nullptr, nullptr, nullptr, 0, cls_b, nullptr, lengths, 0);
}